// Round 3
// baseline (1324.596 us; speedup 1.0000x reference)
//
#include <hip/hip_runtime.h>
#include <math.h>

__device__ __forceinline__ float siluf(float z) {
    return z / (1.0f + __expf(-z));
}
__device__ __forceinline__ float sigmf(float z) {
    return 1.0f / (1.0f + __expf(-z));
}

// Zero the scatter accumulators in workspace and the pot/vdw output slots.
__global__ __launch_bounds__(256) void k_zero(float* __restrict__ ws,
                                              float* __restrict__ potvdw, int n_ws) {
    int i = blockIdx.x * blockDim.x + threadIdx.x;
    if (i < n_ws) ws[i] = 0.0f;
    if (i < 2) potvdw[i] = 0.0f;
}

// Pass 1: per-edge chi / sigma / eps MLPs (64->16->1, 64->32->1, 64->32->1),
// scatter-add into per-node accumulators.
// ONE thread per edge, ONE sweep over x, all 80 hidden accumulators live.
// __launch_bounds__(256, 1) relaxes the allocator's occupancy target so the
// 80 accumulators get real VGPRs (~110) instead of being shuffled through
// AGPRs (round-0: VGPR_Count=72 + AGPR moves -> 3x inner-loop cost), and
// avoids the x re-read of the two-sweep variant (round-2: FETCH 573 MB,
// latency-stalled at VALUBusy 55%).
__global__ __launch_bounds__(256, 1) void k_edge_pass1(
    const float* __restrict__ x, const int* __restrict__ senders,
    const float* __restrict__ Wc1, const float* __restrict__ Wc2,
    const float* __restrict__ Ws1, const float* __restrict__ Ws2,
    const float* __restrict__ We1, const float* __restrict__ We2,
    float* __restrict__ chis, float* __restrict__ sigr, float* __restrict__ epsr,
    int E)
{
    const int e = blockIdx.x * 256 + threadIdx.x;
    if (e >= E) return;
    const float4* x4 = (const float4*)(x + (size_t)e * 64);

    float hc[16], hs[32], he[32];
    #pragma unroll
    for (int j = 0; j < 16; j++) hc[j] = 0.f;
    #pragma unroll
    for (int j = 0; j < 32; j++) { hs[j] = 0.f; he[j] = 0.f; }

    #pragma unroll 4
    for (int q = 0; q < 16; q++) {
        float4 xv = x4[q];
        float xs[4] = {xv.x, xv.y, xv.z, xv.w};
        #pragma unroll
        for (int t = 0; t < 4; t++) {
            const int i = q * 4 + t;
            const float xi = xs[t];
            #pragma unroll
            for (int j = 0; j < 16; j++) hc[j] = fmaf(xi, Wc1[i * 16 + j], hc[j]);
            #pragma unroll
            for (int j = 0; j < 32; j++) hs[j] = fmaf(xi, Ws1[i * 32 + j], hs[j]);
            #pragma unroll
            for (int j = 0; j < 32; j++) he[j] = fmaf(xi, We1[i * 32 + j], he[j]);
        }
    }
    const float s64 = 0.125f;                 // 1/sqrt(64)
    float chi = 0.f, sg = 0.f, ep = 0.f;
    #pragma unroll
    for (int j = 0; j < 16; j++) chi = fmaf(siluf(hc[j] * s64), Wc2[j], chi);
    #pragma unroll
    for (int j = 0; j < 32; j++) sg = fmaf(siluf(hs[j] * s64), Ws2[j], sg);
    #pragma unroll
    for (int j = 0; j < 32; j++) ep = fmaf(siluf(he[j] * s64), We2[j], ep);
    chi *= 0.25f;                              // 1/sqrt(16)
    const float s32i = 0.17677669529663687f;   // 1/sqrt(32)
    sg *= s32i;
    ep *= s32i;

    int s = senders[e];
    atomicAdd(&chis[s], chi);
    atomicAdd(&sigr[s], sg);
    atomicAdd(&epsr[s], ep);
}

// Node stage: charges, pot/vdw reductions, charge-conditioned embedding w[n][16].
__global__ __launch_bounds__(256) void k_nodes(
    const float* __restrict__ chis, const float* __restrict__ sigr,
    const float* __restrict__ epsr,
    const int* __restrict__ species, const float* __restrict__ radius,
    const float* __restrict__ hardness, const float* __restrict__ cembed,
    const float* __restrict__ Ww1,
    float* __restrict__ charges_out, float* __restrict__ w_out,
    float* __restrict__ pot_out, float* __restrict__ vdw_out, int N)
{
    int n = blockIdx.x * 256 + threadIdx.x;
    float potc = 0.f, vdwc = 0.f;
    if (n < N) {
        int sp = species[n];
        float chi = chis[n];
        float gam = fmaf(4.f, radius[sp], 0.5f);
        float hd = hardness[sp];
        // numerically stable softplus
        float hard = fmaxf(hd, 0.f) + log1pf(__expf(-fabsf(hd)));
        float q = -chi / hard;
        potc = 0.5f * (hard + 1.f / gam) * q * q + chi * q;
        float sgv = sigmf(sigr[n]) * 0.15f + 0.15f;
        float epv = sigmf(epsr[n]) * 1.7f + 0.3f;
        vdwc = epv * sgv;
        charges_out[n] = q;

        // w = concat([q, cembed[sp]]) @ (Ww1 / sqrt(17));  Ww1 is [17,16] row-major
        float acc[16];
        #pragma unroll
        for (int k = 0; k < 16; k++) acc[k] = q * Ww1[k];
        #pragma unroll
        for (int i = 0; i < 16; i++) {
            float c = cembed[sp * 16 + i];
            #pragma unroll
            for (int k = 0; k < 16; k++) acc[k] = fmaf(c, Ww1[(i + 1) * 16 + k], acc[k]);
        }
        const float s17 = 0.24253562503633297f; // 1/sqrt(17)
        #pragma unroll
        for (int k = 0; k < 16; k++) w_out[n * 16 + k] = acc[k] * s17;
    }
    // wave reduce (64 lanes) then block reduce pot/vdw
    #pragma unroll
    for (int off = 32; off > 0; off >>= 1) {
        potc += __shfl_down(potc, off, 64);
        vdwc += __shfl_down(vdwc, off, 64);
    }
    __shared__ float sp_[4], sv_[4];
    int wid = threadIdx.x >> 6, lid = threadIdx.x & 63;
    if (lid == 0) { sp_[wid] = potc; sv_[wid] = vdwc; }
    __syncthreads();
    if (threadIdx.x == 0) {
        atomicAdd(pot_out, sp_[0] + sp_[1] + sp_[2] + sp_[3]);
        atomicAdd(vdw_out, sv_[0] + sv_[1] + sv_[2] + sv_[3]);
    }
}

// Pass 2: per-edge 3-layer MLP on concat([x, w[sender]]) + envelope, plus V copy.
// Same allocator relaxation: ~64-80 live values (h[32]+b[32]+staging).
__global__ __launch_bounds__(256, 1) void k_edge_pass2(
    const float* __restrict__ x, const float* __restrict__ V,
    const float* __restrict__ vectors, const int* __restrict__ senders,
    const float* __restrict__ w_nodes,
    const float* __restrict__ Wx1, const float* __restrict__ Wx2,
    const float* __restrict__ Wx3,
    float* __restrict__ xout, float* __restrict__ Vout, int E)
{
    int e = blockIdx.x * 256 + threadIdx.x;
    if (e >= E) return;

    float a[32];
    #pragma unroll
    for (int j = 0; j < 32; j++) a[j] = 0.f;

    const float4* x4 = (const float4*)(x + (size_t)e * 64);
    #pragma unroll 4
    for (int q = 0; q < 16; q++) {
        float4 xv = x4[q];
        float xs[4] = {xv.x, xv.y, xv.z, xv.w};
        #pragma unroll
        for (int t = 0; t < 4; t++) {
            const int i = q * 4 + t;
            const float xi = xs[t];
            #pragma unroll
            for (int j = 0; j < 32; j++) a[j] = fmaf(xi, Wx1[i * 32 + j], a[j]);
        }
    }
    int s = senders[e];
    const float4* w4 = (const float4*)(w_nodes + (size_t)s * 16);
    #pragma unroll
    for (int q = 0; q < 4; q++) {
        float4 wv = w4[q];
        float wsv[4] = {wv.x, wv.y, wv.z, wv.w};
        #pragma unroll
        for (int t = 0; t < 4; t++) {
            const int i = 64 + q * 4 + t;
            const float wi = wsv[t];
            #pragma unroll
            for (int j = 0; j < 32; j++) a[j] = fmaf(wi, Wx1[i * 32 + j], a[j]);
        }
    }
    const float s80 = 0.11180339887498948f;   // 1/sqrt(80)
    const float s32i = 0.17677669529663687f;  // 1/sqrt(32)

    float h[32];
    #pragma unroll
    for (int j = 0; j < 32; j++) h[j] = siluf(a[j] * s80);

    float b[32];
    #pragma unroll
    for (int j = 0; j < 32; j++) b[j] = 0.f;
    #pragma unroll 4
    for (int i = 0; i < 32; i++) {
        const float hi = h[i];
        #pragma unroll
        for (int j = 0; j < 32; j++) b[j] = fmaf(hi, Wx2[i * 32 + j], b[j]);
    }
    #pragma unroll
    for (int j = 0; j < 32; j++) h[j] = siluf(b[j] * s32i);

    #pragma unroll
    for (int j = 0; j < 32; j++) b[j] = 0.f;
    #pragma unroll 4
    for (int i = 0; i < 32; i++) {
        const float hi = h[i];
        #pragma unroll
        for (int j = 0; j < 32; j++) b[j] = fmaf(hi, Wx3[i * 32 + j], b[j]);
    }

    float vx = vectors[(size_t)e * 3 + 0];
    float vy = vectors[(size_t)e * 3 + 1];
    float vz = vectors[(size_t)e * 3 + 2];
    float u = sqrtf(vx * vx + vy * vy + vz * vz);  // MAX_RADIUS = 1
    float env = 0.f;
    if (u < 1.f) {
        float u2 = u * u, u4 = u2 * u2, u6 = u4 * u2;
        env = 1.f + u6 * (-28.f + u * (48.f - 21.f * u));
    }
    const float scale = env * s32i;  // fold layer-3 1/sqrt(32) into envelope

    float4* xo4 = (float4*)(xout + (size_t)e * 32);
    #pragma unroll
    for (int q = 0; q < 8; q++) {
        xo4[q] = make_float4(scale * b[q * 4 + 0], scale * b[q * 4 + 1],
                             scale * b[q * 4 + 2], scale * b[q * 4 + 3]);
    }
    const float4* V4 = (const float4*)(V + (size_t)e * 16);
    float4* Vo4 = (float4*)(Vout + (size_t)e * 16);
    #pragma unroll
    for (int q = 0; q < 4; q++) Vo4[q] = V4[q];
}

extern "C" void kernel_launch(void* const* d_in, const int* in_sizes, int n_in,
                              void* d_out, int out_size, void* d_ws, size_t ws_size,
                              hipStream_t stream)
{
    const float* vectors  = (const float*)d_in[0];
    const float* x        = (const float*)d_in[1];
    const float* V        = (const float*)d_in[2];
    const int*   senders  = (const int*)d_in[3];
    const int*   species  = (const int*)d_in[4];
    const float* radius   = (const float*)d_in[5];
    const float* hardness = (const float*)d_in[6];
    const float* cembed   = (const float*)d_in[7];
    const float* Wc1 = (const float*)d_in[8];
    const float* Wc2 = (const float*)d_in[9];
    const float* Ws1 = (const float*)d_in[10];
    const float* Ws2 = (const float*)d_in[11];
    const float* We1 = (const float*)d_in[12];
    const float* We2 = (const float*)d_in[13];
    const float* Ww1 = (const float*)d_in[14];
    const float* Wx1 = (const float*)d_in[15];
    const float* Wx2 = (const float*)d_in[16];
    const float* Wx3 = (const float*)d_in[17];

    const int E = in_sizes[3];   // senders length
    const int N = in_sizes[4];   // species length

    float* out         = (float*)d_out;
    float* xout        = out;                       // E*32
    float* Vout        = out + (size_t)E * 32;      // E*16
    float* charges_out = out + (size_t)E * 48;      // N
    float* pot_out     = charges_out + N;           // 1
    // vdw_out = pot_out + 1

    float* ws   = (float*)d_ws;
    float* chis = ws;                // N
    float* sigr = ws + N;            // N
    float* epsr = ws + 2 * (size_t)N;// N
    float* wno  = ws + 3 * (size_t)N;// N*16

    const int nzero = 3 * N;
    k_zero<<<(nzero + 255) / 256, 256, 0, stream>>>(ws, pot_out, nzero);
    k_edge_pass1<<<(E + 255) / 256, 256, 0, stream>>>(
        x, senders, Wc1, Wc2, Ws1, Ws2, We1, We2, chis, sigr, epsr, E);
    k_nodes<<<(N + 255) / 256, 256, 0, stream>>>(
        chis, sigr, epsr, species, radius, hardness, cembed, Ww1,
        charges_out, wno, pot_out, pot_out + 1, N);
    k_edge_pass2<<<(E + 255) / 256, 256, 0, stream>>>(
        x, V, vectors, senders, wno, Wx1, Wx2, Wx3, xout, Vout, E);
}

// Round 4
// 1186.906 us; speedup vs baseline: 1.1160x; 1.1160x over previous
//
#include <hip/hip_runtime.h>
#include <math.h>

__device__ __forceinline__ float siluf(float z) {
    return z / (1.0f + __expf(-z));
}
__device__ __forceinline__ float sigmf(float z) {
    return 1.0f / (1.0f + __expf(-z));
}

// Zero the scatter accumulators in workspace and the pot/vdw output slots.
__global__ __launch_bounds__(256) void k_zero(float* __restrict__ ws,
                                              float* __restrict__ potvdw, int n_ws) {
    int i = blockIdx.x * blockDim.x + threadIdx.x;
    if (i < n_ws) ws[i] = 0.0f;
    if (i < 2) potvdw[i] = 0.0f;
}

// Pass 1: per-edge chi / sigma / eps MLPs, scatter-add into node accumulators.
// Block = 256 threads stages a 128-edge x tile into LDS once (single HBM read,
// fixing r2's 573 MB double-fetch), then TWO thread groups share the tile:
//   t in [0,128):   chi(16) + sigma(32)  -> 48 live accumulators
//   t in [128,256): eps(32)             -> 32 live accumulators
// Both stay under the 72-VGPR cliff (r0/r3: 80 acc -> AGPR shuffle, 3x cost),
// weight addresses stay compile-time-uniform -> scalar s_loads (r1 lesson).
// LDS layout [16 float4][128 edges]: compute reads are lane-consecutive 16B
// -> conflict-free; staging writes are 2-way (free, m136).
#define P1_TILE 128
__global__ __launch_bounds__(256) void k_edge_pass1(
    const float* __restrict__ x, const int* __restrict__ senders,
    const float* __restrict__ Wc1, const float* __restrict__ Wc2,
    const float* __restrict__ Ws1, const float* __restrict__ Ws2,
    const float* __restrict__ We1, const float* __restrict__ We2,
    float* __restrict__ chis, float* __restrict__ sigr, float* __restrict__ epsr,
    int E)
{
    __shared__ float4 xs[16][P1_TILE];
    const int t = threadIdx.x;
    const long tile0 = (long)blockIdx.x * P1_TILE;

    // stage 128 rows x 64 floats = 2048 float4, contiguous in global
    const float4* xg = (const float4*)x;
    #pragma unroll
    for (int k = 0; k < 8; k++) {
        const int p = t + k * 256;          // 0..2047 linear in tile
        const int r = p >> 4, q = p & 15;   // q == t & 15 (constant per thread)
        const long e = tile0 + r;
        float4 v = make_float4(0.f, 0.f, 0.f, 0.f);
        if (e < (long)E) v = xg[(size_t)tile0 * 16 + p];
        xs[q][r] = v;
    }
    __syncthreads();

    const int lt = t & (P1_TILE - 1);
    const long e = tile0 + lt;
    const bool valid = (e < (long)E);

    const float s64 = 0.125f;                  // 1/sqrt(64)
    const float s32i = 0.17677669529663687f;   // 1/sqrt(32)

    if (t < P1_TILE) {
        // ---- group A: chi (16) + sigma (32)
        float hc[16], hs[32];
        #pragma unroll
        for (int j = 0; j < 16; j++) hc[j] = 0.f;
        #pragma unroll
        for (int j = 0; j < 32; j++) hs[j] = 0.f;

        #pragma unroll 4
        for (int q = 0; q < 16; q++) {
            float4 xv = xs[q][lt];
            float xsv[4] = {xv.x, xv.y, xv.z, xv.w};
            #pragma unroll
            for (int u = 0; u < 4; u++) {
                const int i = q * 4 + u;
                const float xi = xsv[u];
                #pragma unroll
                for (int j = 0; j < 16; j++) hc[j] = fmaf(xi, Wc1[i * 16 + j], hc[j]);
                #pragma unroll
                for (int j = 0; j < 32; j++) hs[j] = fmaf(xi, Ws1[i * 32 + j], hs[j]);
            }
        }
        float chi = 0.f, sg = 0.f;
        #pragma unroll
        for (int j = 0; j < 16; j++) chi = fmaf(siluf(hc[j] * s64), Wc2[j], chi);
        #pragma unroll
        for (int j = 0; j < 32; j++) sg = fmaf(siluf(hs[j] * s64), Ws2[j], sg);
        if (valid) {
            int s = senders[e];
            atomicAdd(&chis[s], chi * 0.25f);   // 1/sqrt(16)
            atomicAdd(&sigr[s], sg * s32i);
        }
    } else {
        // ---- group B: eps (32)
        float he[32];
        #pragma unroll
        for (int j = 0; j < 32; j++) he[j] = 0.f;

        #pragma unroll 4
        for (int q = 0; q < 16; q++) {
            float4 xv = xs[q][lt];
            float xsv[4] = {xv.x, xv.y, xv.z, xv.w};
            #pragma unroll
            for (int u = 0; u < 4; u++) {
                const int i = q * 4 + u;
                const float xi = xsv[u];
                #pragma unroll
                for (int j = 0; j < 32; j++) he[j] = fmaf(xi, We1[i * 32 + j], he[j]);
            }
        }
        float ep = 0.f;
        #pragma unroll
        for (int j = 0; j < 32; j++) ep = fmaf(siluf(he[j] * s64), We2[j], ep);
        if (valid) {
            int s = senders[e];
            atomicAdd(&epsr[s], ep * s32i);
        }
    }
}

// Node stage: charges, pot/vdw reductions, charge-conditioned embedding w[n][16].
__global__ __launch_bounds__(256) void k_nodes(
    const float* __restrict__ chis, const float* __restrict__ sigr,
    const float* __restrict__ epsr,
    const int* __restrict__ species, const float* __restrict__ radius,
    const float* __restrict__ hardness, const float* __restrict__ cembed,
    const float* __restrict__ Ww1,
    float* __restrict__ charges_out, float* __restrict__ w_out,
    float* __restrict__ pot_out, float* __restrict__ vdw_out, int N)
{
    int n = blockIdx.x * 256 + threadIdx.x;
    float potc = 0.f, vdwc = 0.f;
    if (n < N) {
        int sp = species[n];
        float chi = chis[n];
        float gam = fmaf(4.f, radius[sp], 0.5f);
        float hd = hardness[sp];
        // numerically stable softplus
        float hard = fmaxf(hd, 0.f) + log1pf(__expf(-fabsf(hd)));
        float q = -chi / hard;
        potc = 0.5f * (hard + 1.f / gam) * q * q + chi * q;
        float sgv = sigmf(sigr[n]) * 0.15f + 0.15f;
        float epv = sigmf(epsr[n]) * 1.7f + 0.3f;
        vdwc = epv * sgv;
        charges_out[n] = q;

        // w = concat([q, cembed[sp]]) @ (Ww1 / sqrt(17));  Ww1 is [17,16] row-major
        float acc[16];
        #pragma unroll
        for (int k = 0; k < 16; k++) acc[k] = q * Ww1[k];
        #pragma unroll
        for (int i = 0; i < 16; i++) {
            float c = cembed[sp * 16 + i];
            #pragma unroll
            for (int k = 0; k < 16; k++) acc[k] = fmaf(c, Ww1[(i + 1) * 16 + k], acc[k]);
        }
        const float s17 = 0.24253562503633297f; // 1/sqrt(17)
        #pragma unroll
        for (int k = 0; k < 16; k++) w_out[n * 16 + k] = acc[k] * s17;
    }
    // wave reduce (64 lanes) then block reduce pot/vdw
    #pragma unroll
    for (int off = 32; off > 0; off >>= 1) {
        potc += __shfl_down(potc, off, 64);
        vdwc += __shfl_down(vdwc, off, 64);
    }
    __shared__ float sp_[4], sv_[4];
    int wid = threadIdx.x >> 6, lid = threadIdx.x & 63;
    if (lid == 0) { sp_[wid] = potc; sv_[wid] = vdwc; }
    __syncthreads();
    if (threadIdx.x == 0) {
        atomicAdd(pot_out, sp_[0] + sp_[1] + sp_[2] + sp_[3]);
        atomicAdd(vdw_out, sv_[0] + sv_[1] + sv_[2] + sv_[3]);
    }
}

// Pass 2: per-edge 3-layer MLP on concat([x, w[sender]]) + envelope, plus V copy.
// Layers 2/3 bounce the activation vector through an own-column LDS buffer so
// h[32] and b[32] never coexist in registers (peak live ~44 instead of 64+,
// avoiding the 72-VGPR/AGPR cliff measured on pass1). hb[q][t] accesses are
// lane-consecutive 16B -> conflict-free. Barriers fence the bounce so the
// compiler can't forward the stores back into registers; columns are
// per-thread so there is no cross-thread race.
__global__ __launch_bounds__(256) void k_edge_pass2(
    const float* __restrict__ x, const float* __restrict__ V,
    const float* __restrict__ vectors, const int* __restrict__ senders,
    const float* __restrict__ w_nodes,
    const float* __restrict__ Wx1, const float* __restrict__ Wx2,
    const float* __restrict__ Wx3,
    float* __restrict__ xout, float* __restrict__ Vout, int E)
{
    __shared__ float4 hb[8][256];
    const int t = threadIdx.x;
    const long e = (long)blockIdx.x * 256 + t;
    const bool valid = (e < (long)E);
    const long ec = valid ? e : (long)(E > 0 ? E - 1 : 0);

    const int s = senders[ec];

    float a[32];
    #pragma unroll
    for (int j = 0; j < 32; j++) a[j] = 0.f;

    const float4* x4 = (const float4*)(x + (size_t)ec * 64);
    #pragma unroll 4
    for (int q = 0; q < 16; q++) {
        float4 xv = x4[q];
        float xsv[4] = {xv.x, xv.y, xv.z, xv.w};
        #pragma unroll
        for (int u = 0; u < 4; u++) {
            const int i = q * 4 + u;
            const float xi = xsv[u];
            #pragma unroll
            for (int j = 0; j < 32; j++) a[j] = fmaf(xi, Wx1[i * 32 + j], a[j]);
        }
    }
    const float4* w4 = (const float4*)(w_nodes + (size_t)s * 16);
    #pragma unroll
    for (int q = 0; q < 4; q++) {
        float4 wv = w4[q];
        float wsv[4] = {wv.x, wv.y, wv.z, wv.w};
        #pragma unroll
        for (int u = 0; u < 4; u++) {
            const int i = 64 + q * 4 + u;
            const float wi = wsv[u];
            #pragma unroll
            for (int j = 0; j < 32; j++) a[j] = fmaf(wi, Wx1[i * 32 + j], a[j]);
        }
    }
    const float s80 = 0.11180339887498948f;   // 1/sqrt(80)
    const float s32i = 0.17677669529663687f;  // 1/sqrt(32)

    // silu(layer1) -> LDS bounce
    #pragma unroll
    for (int q = 0; q < 8; q++) {
        hb[q][t] = make_float4(siluf(a[q * 4 + 0] * s80), siluf(a[q * 4 + 1] * s80),
                               siluf(a[q * 4 + 2] * s80), siluf(a[q * 4 + 3] * s80));
    }
    __syncthreads();

    // layer 2: b = h @ Wx2, h streamed from LDS (own column)
    float b[32];
    #pragma unroll
    for (int j = 0; j < 32; j++) b[j] = 0.f;
    #pragma unroll 2
    for (int q = 0; q < 8; q++) {
        float4 hv = hb[q][t];
        float hsv[4] = {hv.x, hv.y, hv.z, hv.w};
        #pragma unroll
        for (int u = 0; u < 4; u++) {
            const int i = q * 4 + u;
            const float hi = hsv[u];
            #pragma unroll
            for (int j = 0; j < 32; j++) b[j] = fmaf(hi, Wx2[i * 32 + j], b[j]);
        }
    }
    // silu(layer2) -> LDS bounce (overwrite own column; no cross-thread race)
    #pragma unroll
    for (int q = 0; q < 8; q++) {
        hb[q][t] = make_float4(siluf(b[q * 4 + 0] * s32i), siluf(b[q * 4 + 1] * s32i),
                               siluf(b[q * 4 + 2] * s32i), siluf(b[q * 4 + 3] * s32i));
    }
    __syncthreads();

    // layer 3: c = g @ Wx3
    float c[32];
    #pragma unroll
    for (int j = 0; j < 32; j++) c[j] = 0.f;
    #pragma unroll 2
    for (int q = 0; q < 8; q++) {
        float4 gv = hb[q][t];
        float gsv[4] = {gv.x, gv.y, gv.z, gv.w};
        #pragma unroll
        for (int u = 0; u < 4; u++) {
            const int i = q * 4 + u;
            const float gi = gsv[u];
            #pragma unroll
            for (int j = 0; j < 32; j++) c[j] = fmaf(gi, Wx3[i * 32 + j], c[j]);
        }
    }

    float vx = vectors[(size_t)ec * 3 + 0];
    float vy = vectors[(size_t)ec * 3 + 1];
    float vz = vectors[(size_t)ec * 3 + 2];
    float u = sqrtf(vx * vx + vy * vy + vz * vz);  // MAX_RADIUS = 1
    float env = 0.f;
    if (u < 1.f) {
        float u2 = u * u, u4 = u2 * u2, u6 = u4 * u2;
        env = 1.f + u6 * (-28.f + u * (48.f - 21.f * u));
    }
    const float scale = env * s32i;  // fold layer-3 1/sqrt(32) into envelope

    if (valid) {
        float4* xo4 = (float4*)(xout + (size_t)e * 32);
        #pragma unroll
        for (int q = 0; q < 8; q++) {
            xo4[q] = make_float4(scale * c[q * 4 + 0], scale * c[q * 4 + 1],
                                 scale * c[q * 4 + 2], scale * c[q * 4 + 3]);
        }
        const float4* V4 = (const float4*)(V + (size_t)e * 16);
        float4* Vo4 = (float4*)(Vout + (size_t)e * 16);
        #pragma unroll
        for (int q = 0; q < 4; q++) Vo4[q] = V4[q];
    }
}

extern "C" void kernel_launch(void* const* d_in, const int* in_sizes, int n_in,
                              void* d_out, int out_size, void* d_ws, size_t ws_size,
                              hipStream_t stream)
{
    const float* vectors  = (const float*)d_in[0];
    const float* x        = (const float*)d_in[1];
    const float* V        = (const float*)d_in[2];
    const int*   senders  = (const int*)d_in[3];
    const int*   species  = (const int*)d_in[4];
    const float* radius   = (const float*)d_in[5];
    const float* hardness = (const float*)d_in[6];
    const float* cembed   = (const float*)d_in[7];
    const float* Wc1 = (const float*)d_in[8];
    const float* Wc2 = (const float*)d_in[9];
    const float* Ws1 = (const float*)d_in[10];
    const float* Ws2 = (const float*)d_in[11];
    const float* We1 = (const float*)d_in[12];
    const float* We2 = (const float*)d_in[13];
    const float* Ww1 = (const float*)d_in[14];
    const float* Wx1 = (const float*)d_in[15];
    const float* Wx2 = (const float*)d_in[16];
    const float* Wx3 = (const float*)d_in[17];

    const int E = in_sizes[3];   // senders length
    const int N = in_sizes[4];   // species length

    float* out         = (float*)d_out;
    float* xout        = out;                       // E*32
    float* Vout        = out + (size_t)E * 32;      // E*16
    float* charges_out = out + (size_t)E * 48;      // N
    float* pot_out     = charges_out + N;           // 1
    // vdw_out = pot_out + 1

    float* ws   = (float*)d_ws;
    float* chis = ws;                // N
    float* sigr = ws + N;            // N
    float* epsr = ws + 2 * (size_t)N;// N
    float* wno  = ws + 3 * (size_t)N;// N*16

    const int nzero = 3 * N;
    k_zero<<<(nzero + 255) / 256, 256, 0, stream>>>(ws, pot_out, nzero);
    // 128 edges per 256-thread block: two groups share one LDS x tile
    k_edge_pass1<<<(E + P1_TILE - 1) / P1_TILE, 256, 0, stream>>>(
        x, senders, Wc1, Wc2, Ws1, Ws2, We1, We2, chis, sigr, epsr, E);
    k_nodes<<<(N + 255) / 256, 256, 0, stream>>>(
        chis, sigr, epsr, species, radius, hardness, cembed, Ww1,
        charges_out, wno, pot_out, pot_out + 1, N);
    k_edge_pass2<<<(E + 255) / 256, 256, 0, stream>>>(
        x, V, vectors, senders, wno, Wx1, Wx2, Wx3, xout, Vout, E);
}